// Round 1
// baseline (36.013 us; speedup 1.0000x reference)
//
#include <hip/hip_runtime.h>
#include <math.h>

#define H 4096
#define NSTEPS 1000
#define NT 256
#define JPT 16   // H / NT hidden units per thread

__global__ __launch_bounds__(NT, 1) void sketch_kernel(
    const float* __restrict__ W_ih,
    const float* __restrict__ b_ih,
    const float* __restrict__ b_hh,
    const float* __restrict__ W_lin,
    const float* __restrict__ b_lin,
    const float* __restrict__ noise,
    float* __restrict__ out)
{
    const int tid  = threadIdx.x;
    const int lane = tid & 63;
    const int wave = tid >> 6;

    __shared__ float s_noise[NSTEPS * 2];
    __shared__ float s_part[4][8];
    __shared__ float s_prev[8];

    for (int i = tid; i < NSTEPS * 2; i += NT) s_noise[i] = noise[i];

    // Preload this thread's weight slice into registers.
    // Only i, g, o gates are live (f-gate output is never used; W_hh @ h == 0).
    float wI[JPT][5], wG[JPT][5], wO[JPT][5];
    float bI[JPT], bG[JPT], bO[JPT];
    float wL[7][JPT];
#pragma unroll
    for (int k = 0; k < JPT; ++k) {
        const int j = tid + k * NT;
#pragma unroll
        for (int c = 0; c < 5; ++c) {
            wI[k][c] = W_ih[j * 5 + c];
            wG[k][c] = W_ih[(2 * H + j) * 5 + c];
            wO[k][c] = W_ih[(3 * H + j) * 5 + c];
        }
        bI[k] = b_ih[j] + b_hh[j];
        bG[k] = b_ih[2 * H + j] + b_hh[2 * H + j];
        bO[k] = b_ih[3 * H + j] + b_hh[3 * H + j];
#pragma unroll
        for (int l = 0; l < 7; ++l) wL[l][k] = W_lin[l * H + j];
    }

    if (tid == 0) {
        out[0] = 0.f; out[1] = 0.f; out[2] = 1.f; out[3] = 0.f; out[4] = 0.f;
    }
    __syncthreads();

    float pv0 = 0.f, pv1 = 0.f, pv2 = 1.f, pv3 = 0.f, pv4 = 0.f;

    int t;
    for (t = 0; t < NSTEPS; ++t) {
        float a0 = 0.f, a1 = 0.f, a2 = 0.f, a3 = 0.f, a4 = 0.f, a5 = 0.f, a6 = 0.f;
#pragma unroll
        for (int k = 0; k < JPT; ++k) {
            float gi = fmaf(wI[k][4], pv4, fmaf(wI[k][3], pv3, fmaf(wI[k][2], pv2, fmaf(wI[k][1], pv1, fmaf(wI[k][0], pv0, bI[k])))));
            float gg = fmaf(wG[k][4], pv4, fmaf(wG[k][3], pv3, fmaf(wG[k][2], pv2, fmaf(wG[k][1], pv1, fmaf(wG[k][0], pv0, bG[k])))));
            float go = fmaf(wO[k][4], pv4, fmaf(wO[k][3], pv3, fmaf(wO[k][2], pv2, fmaf(wO[k][1], pv1, fmaf(wO[k][0], pv0, bO[k])))));
            // c = sigmoid(gi) * tanh(gg); one fast-div for the combined denominator
            float ei = __expf(-gi);              // v_exp_f32
            float eg = __expf(gg + gg);
            float cg = __fdividef(eg - 1.f, (1.f + ei) * (eg + 1.f));
            // h = sigmoid(go) * tanh(c)
            float eo = __expf(-go);
            float ec = __expf(cg + cg);
            float hj = __fdividef(ec - 1.f, (1.f + eo) * (ec + 1.f));
            a0 = fmaf(wL[0][k], hj, a0);
            a1 = fmaf(wL[1][k], hj, a1);
            a2 = fmaf(wL[2][k], hj, a2);
            a3 = fmaf(wL[3][k], hj, a3);
            a4 = fmaf(wL[4][k], hj, a4);
            a5 = fmaf(wL[5][k], hj, a5);
            a6 = fmaf(wL[6][k], hj, a6);
        }
        // In-wave butterfly reduce (deterministic; no atomics)
#pragma unroll
        for (int m = 1; m < 64; m <<= 1) {
            a0 += __shfl_xor(a0, m, 64);
            a1 += __shfl_xor(a1, m, 64);
            a2 += __shfl_xor(a2, m, 64);
            a3 += __shfl_xor(a3, m, 64);
            a4 += __shfl_xor(a4, m, 64);
            a5 += __shfl_xor(a5, m, 64);
            a6 += __shfl_xor(a6, m, 64);
        }
        if (lane == 0) {
            s_part[wave][0] = a0; s_part[wave][1] = a1; s_part[wave][2] = a2;
            s_part[wave][3] = a3; s_part[wave][4] = a4; s_part[wave][5] = a5;
            s_part[wave][6] = a6;
        }
        __syncthreads();
        if (tid == 0) {
            float lg[7];
#pragma unroll
            for (int l = 0; l < 7; ++l) {
                float s = s_part[0][l] + s_part[1][l] + s_part[2][l] + s_part[3][l] + b_lin[l];
                lg[l] = tanhf(s);   // precise tail: only 7 values/step
            }
            float mx = fmaxf(lg[4], fmaxf(lg[5], lg[6]));
            float e0 = expf(lg[4] - mx), e1 = expf(lg[5] - mx), e2 = expf(lg[6] - mx);
            float inv = 1.f / (e0 + e1 + e2);
            float p0 = e0 * inv, p1 = e1 * inv, p2 = e2 * inv;
            float x0 = lg[0] + expf(lg[1] * 0.5f) * s_noise[2 * t];
            float x1 = lg[2] + expf(lg[3] * 0.5f) * s_noise[2 * t + 1];
            float* row = out + (t + 1) * 5;
            row[0] = x0; row[1] = x1; row[2] = p0; row[3] = p1; row[4] = p2;
            s_prev[0] = x0; s_prev[1] = x1; s_prev[2] = p0; s_prev[3] = p1; s_prev[4] = p2;
            // argmax(new_row[2:]) == 2 iff p2 strictly beats both (jnp.argmax ties -> first index)
            s_prev[5] = (p2 > p0 && p2 > p1) ? 1.f : 0.f;
        }
        __syncthreads();
        pv0 = s_prev[0]; pv1 = s_prev[1]; pv2 = s_prev[2]; pv3 = s_prev[3]; pv4 = s_prev[4];
        if (s_prev[5] != 0.f) break;   // uniform across block
    }

    // Rows after the stop step are zero. If no stop: t == NSTEPS -> start > 5005, no-op.
    const int start = (t + 2) * 5;
    for (int i = start + tid; i < (NSTEPS + 1) * 5; i += NT) out[i] = 0.f;
}

extern "C" void kernel_launch(void* const* d_in, const int* in_sizes, int n_in,
                              void* d_out, int out_size, void* d_ws, size_t ws_size,
                              hipStream_t stream) {
    const float* W_ih  = (const float*)d_in[0];
    // d_in[1] = W_hh: mathematically dead (h = c = 0 every step) — never read.
    const float* b_ih  = (const float*)d_in[2];
    const float* b_hh  = (const float*)d_in[3];
    const float* W_lin = (const float*)d_in[4];
    const float* b_lin = (const float*)d_in[5];
    const float* noise = (const float*)d_in[6];
    float* out = (float*)d_out;

    hipLaunchKernelGGL(sketch_kernel, dim3(1), dim3(NT), 0, stream,
                       W_ih, b_ih, b_hh, W_lin, b_lin, noise, out);
}

// Round 2
// 28.310 us; speedup vs baseline: 1.2721x; 1.2721x over previous
//
#include <hip/hip_runtime.h>
#include <math.h>

#define H 4096
#define NSTEPS 1000
#define NT 512
#define JPT 8    // H / NT contiguous hidden units per thread

__global__ __launch_bounds__(NT, 1) void sketch_kernel(
    const float* __restrict__ W_ih,
    const float* __restrict__ b_ih,
    const float* __restrict__ b_hh,
    const float* __restrict__ W_lin,
    const float* __restrict__ b_lin,
    const float* __restrict__ noise,
    float* __restrict__ out)
{
    const int tid  = threadIdx.x;
    const int lane = tid & 63;
    const int wave = tid >> 6;                 // 8 waves
    const int j0   = tid * JPT;                // contiguous row block

    __shared__ float s_noise[NSTEPS * 2];
    __shared__ float s_part[8][8];             // [wave][logit]
    __shared__ float s_prev[8];

    for (int i = tid; i < NSTEPS * 2; i += NT) s_noise[i] = noise[i];

    // ---- register-resident weights, loaded as aligned float4 ----
    // Live rows: i-gate [j0..j0+8), g-gate [2H+j0..), o-gate [3H+j0..).
    // Each gate slice = 40 consecutive floats = 10 float4 (160B, 16B-aligned).
    float wi[40], wg[40], wo[40];
    {
        const float4* pi = (const float4*)(W_ih + (size_t)j0 * 5);
        const float4* pg = (const float4*)(W_ih + (size_t)(2 * H + j0) * 5);
        const float4* po = (const float4*)(W_ih + (size_t)(3 * H + j0) * 5);
#pragma unroll
        for (int q = 0; q < 10; ++q) {
            float4 vi = pi[q], vg = pg[q], vo = po[q];
            wi[4*q+0] = vi.x; wi[4*q+1] = vi.y; wi[4*q+2] = vi.z; wi[4*q+3] = vi.w;
            wg[4*q+0] = vg.x; wg[4*q+1] = vg.y; wg[4*q+2] = vg.z; wg[4*q+3] = vg.w;
            wo[4*q+0] = vo.x; wo[4*q+1] = vo.y; wo[4*q+2] = vo.z; wo[4*q+3] = vo.w;
        }
    }
    float bI[JPT], bG[JPT], bO[JPT];
    {
        const float4* a0 = (const float4*)(b_ih + j0);
        const float4* a1 = (const float4*)(b_hh + j0);
        const float4* g0 = (const float4*)(b_ih + 2 * H + j0);
        const float4* g1 = (const float4*)(b_hh + 2 * H + j0);
        const float4* o0 = (const float4*)(b_ih + 3 * H + j0);
        const float4* o1 = (const float4*)(b_hh + 3 * H + j0);
#pragma unroll
        for (int q = 0; q < 2; ++q) {
            float4 x = a0[q], y = a1[q];
            bI[4*q+0] = x.x + y.x; bI[4*q+1] = x.y + y.y; bI[4*q+2] = x.z + y.z; bI[4*q+3] = x.w + y.w;
            x = g0[q]; y = g1[q];
            bG[4*q+0] = x.x + y.x; bG[4*q+1] = x.y + y.y; bG[4*q+2] = x.z + y.z; bG[4*q+3] = x.w + y.w;
            x = o0[q]; y = o1[q];
            bO[4*q+0] = x.x + y.x; bO[4*q+1] = x.y + y.y; bO[4*q+2] = x.z + y.z; bO[4*q+3] = x.w + y.w;
        }
    }
    float wl[7][JPT];
#pragma unroll
    for (int l = 0; l < 7; ++l) {
        const float4* p = (const float4*)(W_lin + (size_t)l * H + j0);
#pragma unroll
        for (int q = 0; q < 2; ++q) {
            float4 v = p[q];
            wl[l][4*q+0] = v.x; wl[l][4*q+1] = v.y; wl[l][4*q+2] = v.z; wl[l][4*q+3] = v.w;
        }
    }
    const float blin = (lane < 7 && wave == 0) ? b_lin[lane] : 0.f;

    if (tid == 0) {
        out[0] = 0.f; out[1] = 0.f; out[2] = 1.f; out[3] = 0.f; out[4] = 0.f;
    }
    __syncthreads();

    float pv0 = 0.f, pv1 = 0.f, pv2 = 1.f, pv3 = 0.f, pv4 = 0.f;

    int t;
    for (t = 0; t < NSTEPS; ++t) {
        float a0 = 0.f, a1 = 0.f, a2 = 0.f, a3 = 0.f, a4 = 0.f, a5 = 0.f, a6 = 0.f;
#pragma unroll
        for (int r = 0; r < JPT; ++r) {
            float gi = fmaf(wi[r*5+4], pv4, fmaf(wi[r*5+3], pv3, fmaf(wi[r*5+2], pv2, fmaf(wi[r*5+1], pv1, fmaf(wi[r*5+0], pv0, bI[r])))));
            float gg = fmaf(wg[r*5+4], pv4, fmaf(wg[r*5+3], pv3, fmaf(wg[r*5+2], pv2, fmaf(wg[r*5+1], pv1, fmaf(wg[r*5+0], pv0, bG[r])))));
            float go = fmaf(wo[r*5+4], pv4, fmaf(wo[r*5+3], pv3, fmaf(wo[r*5+2], pv2, fmaf(wo[r*5+1], pv1, fmaf(wo[r*5+0], pv0, bO[r])))));
            float ei = __expf(-gi);
            float eg = __expf(gg + gg);
            float cg = __fdividef(eg - 1.f, (1.f + ei) * (eg + 1.f));   // sig(i)*tanh(g)
            float eo = __expf(-go);
            float ec = __expf(cg + cg);
            float hj = __fdividef(ec - 1.f, (1.f + eo) * (ec + 1.f));   // sig(o)*tanh(c)
            a0 = fmaf(wl[0][r], hj, a0);
            a1 = fmaf(wl[1][r], hj, a1);
            a2 = fmaf(wl[2][r], hj, a2);
            a3 = fmaf(wl[3][r], hj, a3);
            a4 = fmaf(wl[4][r], hj, a4);
            a5 = fmaf(wl[5][r], hj, a5);
            a6 = fmaf(wl[6][r], hj, a6);
        }
#pragma unroll
        for (int m = 1; m < 64; m <<= 1) {
            a0 += __shfl_xor(a0, m, 64);
            a1 += __shfl_xor(a1, m, 64);
            a2 += __shfl_xor(a2, m, 64);
            a3 += __shfl_xor(a3, m, 64);
            a4 += __shfl_xor(a4, m, 64);
            a5 += __shfl_xor(a5, m, 64);
            a6 += __shfl_xor(a6, m, 64);
        }
        if (lane == 0) {
            s_part[wave][0] = a0; s_part[wave][1] = a1; s_part[wave][2] = a2;
            s_part[wave][3] = a3; s_part[wave][4] = a4; s_part[wave][5] = a5;
            s_part[wave][6] = a6;
        }
        __syncthreads();
        if (wave == 0) {
            // lanes 0..6 each finish one logit (cross-wave sum + tanh via HW exp)
            const int l = lane < 7 ? lane : 0;
            float s = blin;
#pragma unroll
            for (int w = 0; w < 8; ++w) s += s_part[w][l];
            float e2 = __expf(s + s);
            float lg = __fdividef(e2 - 1.f, e2 + 1.f);
            // gather to lane 0 (wave-local, no barrier)
            float l0 = __shfl(lg, 0, 64), l1 = __shfl(lg, 1, 64), l2 = __shfl(lg, 2, 64);
            float l3 = __shfl(lg, 3, 64), l4 = __shfl(lg, 4, 64), l5 = __shfl(lg, 5, 64);
            float l6 = __shfl(lg, 6, 64);
            if (lane == 0) {
                float mx = fmaxf(l4, fmaxf(l5, l6));
                float e0 = __expf(l4 - mx), e1 = __expf(l5 - mx), e2b = __expf(l6 - mx);
                float inv = __fdividef(1.f, e0 + e1 + e2b);
                float p0 = e0 * inv, p1 = e1 * inv, p2 = e2b * inv;
                float x0 = l0 + __expf(l1 * 0.5f) * s_noise[2 * t];
                float x1 = l2 + __expf(l3 * 0.5f) * s_noise[2 * t + 1];
                float* row = out + (t + 1) * 5;
                row[0] = x0; row[1] = x1; row[2] = p0; row[3] = p1; row[4] = p2;
                s_prev[0] = x0; s_prev[1] = x1; s_prev[2] = p0; s_prev[3] = p1; s_prev[4] = p2;
                // argmax(new_row[2:]) == 2 (numpy first-index ties) iff p2 strictly beats p0 and p1
                s_prev[5] = (p2 > p0 && p2 > p1) ? 1.f : 0.f;
            }
        }
        __syncthreads();
        pv0 = s_prev[0]; pv1 = s_prev[1]; pv2 = s_prev[2]; pv3 = s_prev[3]; pv4 = s_prev[4];
        if (s_prev[5] != 0.f) break;   // uniform across block
    }

    // zero rows after the stop step (t==NSTEPS -> start past end, no-op)
    const int start = (t + 2) * 5;
    for (int i = start + tid; i < (NSTEPS + 1) * 5; i += NT) out[i] = 0.f;
}

extern "C" void kernel_launch(void* const* d_in, const int* in_sizes, int n_in,
                              void* d_out, int out_size, void* d_ws, size_t ws_size,
                              hipStream_t stream) {
    const float* W_ih  = (const float*)d_in[0];
    // d_in[1] = W_hh: mathematically dead (h = c = 0 every step) — never read.
    const float* b_ih  = (const float*)d_in[2];
    const float* b_hh  = (const float*)d_in[3];
    const float* W_lin = (const float*)d_in[4];
    const float* b_lin = (const float*)d_in[5];
    const float* noise = (const float*)d_in[6];
    float* out = (float*)d_out;

    hipLaunchKernelGGL(sketch_kernel, dim3(1), dim3(NT), 0, stream,
                       W_ih, b_ih, b_hh, W_lin, b_lin, noise, out);
}